// Round 2
// baseline (321.273 us; speedup 1.0000x reference)
//
#include <hip/hip_runtime.h>

#define DEVI __device__ __forceinline__

typedef _Float16 f16x8 __attribute__((ext_vector_type(8)));
typedef _Float16 f16x4v __attribute__((ext_vector_type(4)));
typedef _Float16 f16x2 __attribute__((ext_vector_type(2)));
typedef float f32x4 __attribute__((ext_vector_type(4)));

DEVI void gl16(const void* g, void* l) {
  __builtin_amdgcn_global_load_lds((const __attribute__((address_space(1))) void*)g,
                                   (__attribute__((address_space(3))) void*)l, 16, 0, 0);
}

#define VMCNT(N) asm volatile("s_waitcnt vmcnt(" #N ")" ::: "memory")
#define BARRIER() asm volatile("s_barrier" ::: "memory")

// ---------------- f32 -> f16 convert ----------------
__global__ __launch_bounds__(256) void k_cvt(const float* __restrict__ in, _Float16* __restrict__ out, int n4) {
  int i = blockIdx.x * 256 + threadIdx.x;
  int stride = gridDim.x * 256;
  for (; i < n4; i += stride) {
    float4 v = ((const float4*)in)[i];
    f16x4v h = { (_Float16)v.x, (_Float16)v.y, (_Float16)v.z, (_Float16)v.w };
    ((f16x4v*)out)[i] = h;
  }
}

// ---------------- transpose + convert: in[R][C] f32 -> out[C][R] f16 ----------------
__global__ __launch_bounds__(256) void k_transpose(const float* __restrict__ in, _Float16* __restrict__ out,
                                                   int R, int C) {
  __shared__ float t[32][33];
  int cb = blockIdx.x * 32, rb = blockIdx.y * 32;
  int tx = threadIdx.x & 31, ty = threadIdx.x >> 5;
  #pragma unroll
  for (int i = ty; i < 32; i += 8) t[i][tx] = in[(size_t)(rb + i) * C + cb + tx];
  __syncthreads();
  #pragma unroll
  for (int i = ty; i < 32; i += 8) out[(size_t)(cb + i) * R + rb + tx] = (_Float16)t[tx][i];
}

// ================= 256x256 8-phase GEMM: C[M,N] = A[M,K] * BT[N,K]^T + bias =================
// 512 threads = 8 waves (2 Mwaves x 4 Nwaves); per-wave output 128x64 (8x4 16x16 frags).
// LDS 128 KiB: A/B each 2 dbuf x 2 half x [128][64] f16, XOR chunk-swizzled (ch ^= row&7),
// staged via global_load_lds(16B) with pre-swizzled global source. Counted vmcnt, never 0.
// EPI=0: write fp32 outF. EPI=1: scatter q/k/v (q scaled by 1/sqrt(80)).

#define MM(NLO, AF, BF) do {                                                                       \
    __builtin_amdgcn_s_setprio(1);                                                                 \
    _Pragma("unroll")                                                                              \
    for (int m_ = 0; m_ < 8; m_++) {                                                               \
      acc[m_][NLO]     = __builtin_amdgcn_mfma_f32_16x16x32_f16(AF[m_], BF[NLO],     acc[m_][NLO],     0, 0, 0); \
      acc[m_][NLO + 1] = __builtin_amdgcn_mfma_f32_16x16x32_f16(AF[m_], BF[NLO + 1], acc[m_][NLO + 1], 0, 0, 0); \
    }                                                                                              \
    __builtin_amdgcn_s_setprio(0);                                                                 \
  } while (0)

#define LDA(KT, KK, DST) do {                                                                      \
    const _Float16* bas_ = &smem[(size_t)((((KT) & 1) * 2) + wr) * 8192];                          \
    _Pragma("unroll")                                                                              \
    for (int m_ = 0; m_ < 8; m_++)                                                                 \
      DST[m_] = *(const f16x8*)&bas_[(m_ * 16 + ln) * 64 + (((((KK) * 4) + g) ^ chB) << 3)];       \
  } while (0)

#define LDB(KT, KK, DST) do {                                                                      \
    const _Float16* bas_ = &smem[32768 + (size_t)((((KT) & 1) * 2) + (wc >> 1)) * 8192];           \
    _Pragma("unroll")                                                                              \
    for (int n_ = 0; n_ < 4; n_++)                                                                 \
      DST[n_] = *(const f16x8*)&bas_[((wc & 1) * 64 + n_ * 16 + ln) * 64 + (((((KK) * 4) + g) ^ chB) << 3)]; \
  } while (0)

template<int M, int N, int K, int EPI>
__global__ __launch_bounds__(512, 2) void k_gemm8(const _Float16* __restrict__ A, const _Float16* __restrict__ BT,
                                                  const float* __restrict__ bias, float* __restrict__ outF,
                                                  _Float16* __restrict__ qo, _Float16* __restrict__ ko,
                                                  _Float16* __restrict__ vo) {
  extern __shared__ _Float16 smem[];  // [0,32768): A   [32768,65536): B
  constexpr int NT = K / 64;   // K-tiles
  constexpr int NI = NT / 2;   // iterations (2 tiles each)
  const int tid = threadIdx.x;
  const int w = tid >> 6, lane = tid & 63, ln = lane & 15, g = lane >> 4;
  const int wr = w >> 2, wc = w & 3;
  const int l8 = lane >> 3, l7 = lane & 7;
  const int stChunk = (l7 ^ l8) << 3;  // pre-swizzled source chunk (elements)
  const int chB = ln & 7;              // read-side swizzle key

  // XCD-aware bijective block swizzle (grid counts divisible by 8)
  constexpr int nbx = M / 256, nby = N / 256, nwg = nbx * nby, cpx = nwg / 8;
  int bid = blockIdx.x;
  int swz = (bid & 7) * cpx + (bid >> 3);
  const int bm0 = (swz % nbx) * 256, bn0 = (swz / nbx) * 256;

  auto stgA = [&](int kt, int hh) {
    _Float16* ldsb = &smem[(size_t)((kt & 1) * 2 + hh) * 8192 + w * 1024];
    const _Float16* g0 = &A[(size_t)(bm0 + hh * 128 + w * 16 + l8) * K + kt * 64 + stChunk];
    gl16(g0, ldsb);
    gl16(g0 + (size_t)8 * K, ldsb + 512);
  };
  auto stgB = [&](int kt, int hh) {
    _Float16* ldsb = &smem[32768 + (size_t)((kt & 1) * 2 + hh) * 8192 + w * 1024];
    const _Float16* g0 = &BT[(size_t)(bn0 + hh * 128 + w * 16 + l8) * K + kt * 64 + stChunk];
    gl16(g0, ldsb);
    gl16(g0 + (size_t)8 * K, ldsb + 512);
  };

  f32x4 acc[8][4] = {};
  f16x8 a0[8], a1[8], b0[4], b1[4];  // bank0 = kk0, bank1 = kk1 of current tile

  // ---- prologue: stage tile0 fully + tile1 (B both halves, A half0); A1h1 comes at ph1 ----
  stgB(0, 0); stgB(0, 1); stgA(0, 0); stgA(0, 1);
  stgB(1, 0); stgB(1, 1); stgA(1, 0);
  VMCNT(6);      // tile0's 8 loads (oldest) landed
  BARRIER();
  LDA(0, 0, a0); LDB(0, 0, b0);

  for (int it = 0; it < NI; ++it) {
    const int T0 = 2 * it, T1 = 2 * it + 1;
    const int S0 = (T0 + 2 < NT) ? T0 + 2 : 0;  // wrap keeps parity; wrapped data never read
    const int S1 = (T1 + 2 < NT) ? T1 + 2 : 1;
    // ph1
    LDB(T0, 1, b1);
    stgA(T1, 1);
    BARRIER();
    MM(0, a0, b0);
    BARRIER();
    // ph2
    LDA(T0, 1, a1);
    stgB(S0, 0);
    BARRIER();
    MM(2, a0, b0);
    BARRIER();
    // ph3
    stgB(S0, 1);
    BARRIER();
    MM(0, a1, b1);
    VMCNT(4);    // lands A(T1)h0/h1 (ph8-prev, ph1) before ph4's reads
    BARRIER();
    // ph4
    LDA(T1, 0, a0); LDB(T1, 0, b0);
    stgA(S0, 0);
    BARRIER();
    MM(2, a1, b1);
    BARRIER();
    // ph5
    LDB(T1, 1, b1);
    stgA(S0, 1);
    BARRIER();
    MM(0, a0, b0);
    BARRIER();
    // ph6
    LDA(T1, 1, a1);
    stgB(S1, 0);
    BARRIER();
    MM(2, a0, b0);
    BARRIER();
    // ph7
    stgB(S1, 1);
    BARRIER();
    MM(0, a1, b1);
    VMCNT(4);    // lands A(S0)h0/h1 (+B(S0)h1) before ph8's reads
    BARRIER();
    // ph8
    LDA(S0, 0, a0); LDB(S0, 0, b0);
    stgA(S1, 0);
    BARRIER();
    MM(2, a1, b1);
    BARRIER();
  }

  // ---- epilogue ----
  if (EPI == 0) {
    #pragma unroll
    for (int n = 0; n < 4; n++) {
      int col = bn0 + wc * 64 + n * 16 + ln;
      float bv = bias[col];
      #pragma unroll
      for (int m = 0; m < 8; m++) {
        int rbase = bm0 + wr * 128 + m * 16 + 4 * g;
        #pragma unroll
        for (int r = 0; r < 4; r++)
          outF[(size_t)(rbase + r) * N + col] = acc[m][n][r] + bv;
      }
    }
  } else {
    #pragma unroll
    for (int n = 0; n < 4; n++) {
      int col = bn0 + wc * 64 + n * 16 + ln;
      float bv = bias[col];
      int h = col / 240;
      int tt = col - h * 240;
      int reg = tt / 80;
      int cc = tt - reg * 80;
      #pragma unroll
      for (int m = 0; m < 8; m++) {
        #pragma unroll
        for (int r = 0; r < 4; r++) {
          int row = bm0 + wr * 128 + m * 16 + 4 * g + r;
          int s = row >> 3, bbm = row & 7;
          int head = bbm * 16 + h;
          float val = acc[m][n][r] + bv;
          if (reg == 0)      qo[(head * 1024 + s) * 96 + cc] = (_Float16)(val * 0.11180339887498948f);
          else if (reg == 1) ko[(head * 1024 + s) * 96 + cc] = (_Float16)val;
          else               vo[(head * 1024 + s) * 80 + cc] = (_Float16)val;
        }
      }
    }
  }
}

// ---------------- per-head V transpose: vb[head][1024][80] -> vT[head][80][1024] ----------------
__global__ __launch_bounds__(256) void k_vtrans(const _Float16* __restrict__ vb, _Float16* __restrict__ vT) {
  __shared__ _Float16 t[64][81];
  int head = blockIdx.x >> 4;
  int sb = (blockIdx.x & 15) * 64;
  for (int idx = threadIdx.x; idx < 64 * 80; idx += 256) {
    int s = idx / 80, d = idx - s * 80;
    t[s][d] = vb[(head * 1024 + sb + s) * 80 + d];
  }
  __syncthreads();
  for (int idx = threadIdx.x; idx < 80 * 64; idx += 256) {
    int d = idx >> 6, s = idx & 63;
    vT[(head * 80 + d) * 1024 + sb + s] = t[s][d];
  }
}

// ---------------- flash attention ----------------
// qb/kb: [head][1024][96] (f16, cols 80..95 zero; q pre-scaled), vT: [head][80][1024]
// ctxg: [s][b][h*80+d] f16  == [8192][1280]
__global__ __launch_bounds__(256) void k_attn(const _Float16* __restrict__ qb, const _Float16* __restrict__ kb,
                                              const _Float16* __restrict__ vT, _Float16* __restrict__ ctxg) {
  __shared__ _Float16 Kl[64 * 104];
  __shared__ _Float16 Vl[80 * 72];
  __shared__ _Float16 Pl[64 * 72];
  const int tid = threadIdx.x;
  const int w = tid >> 6, lane = tid & 63, ln = lane & 15, g = lane >> 4;
  const int head = blockIdx.x >> 4;
  const int s0 = (blockIdx.x & 15) * 64;
  const int bb = head >> 4, h = head & 15;

  const int qrow = s0 + w * 16 + ln;
  f16x8 qf[3];
  #pragma unroll
  for (int dc = 0; dc < 3; ++dc)
    qf[dc] = *(const f16x8*)&qb[(head * 1024 + qrow) * 96 + dc * 32 + g * 8];

  f32x4 ctxa[5] = {};
  float m_run = -INFINITY, l_run = 0.f;

  for (int kt2 = 0; kt2 < 16; ++kt2) {
    __syncthreads();
    #pragma unroll
    for (int jj = 0; jj < 3; ++jj) {
      int c = tid + jj * 256;
      int row = c / 12, ch = c - row * 12;
      *(uint4*)&Kl[row * 104 + ch * 8] = *(const uint4*)&kb[(head * 1024 + kt2 * 64 + row) * 96 + ch * 8];
    }
    #pragma unroll
    for (int jj = 0; jj < 3; ++jj) {
      int c = tid + jj * 256;
      if (c < 640) {
        int row = c >> 3, ch = c & 7;
        *(uint4*)&Vl[row * 72 + ch * 8] = *(const uint4*)&vT[(head * 80 + row) * 1024 + kt2 * 64 + ch * 8];
      }
    }
    __syncthreads();
    f32x4 sc[4] = {};
    #pragma unroll
    for (int t16 = 0; t16 < 4; ++t16)
      #pragma unroll
      for (int dc = 0; dc < 3; ++dc) {
        f16x8 kf = *(const f16x8*)&Kl[(t16 * 16 + ln) * 104 + dc * 32 + g * 8];
        sc[t16] = __builtin_amdgcn_mfma_f32_16x16x32_f16(kf, qf[dc], sc[t16], 0, 0, 0);
      }
    float tm = -INFINITY;
    #pragma unroll
    for (int t16 = 0; t16 < 4; ++t16)
      #pragma unroll
      for (int r = 0; r < 4; ++r) tm = fmaxf(tm, sc[t16][r]);
    tm = fmaxf(tm, __shfl_xor(tm, 16));
    tm = fmaxf(tm, __shfl_xor(tm, 32));
    float mnew = fmaxf(m_run, tm);
    float fac = __expf(m_run - mnew);
    float ps = 0.f;
    #pragma unroll
    for (int t16 = 0; t16 < 4; ++t16) {
      float p0 = __expf(sc[t16][0] - mnew);
      float p1 = __expf(sc[t16][1] - mnew);
      float p2 = __expf(sc[t16][2] - mnew);
      float p3 = __expf(sc[t16][3] - mnew);
      ps += (p0 + p1) + (p2 + p3);
      int off = (w * 16 + ln) * 72 + t16 * 16 + g * 4;
      f16x2 w01 = { (_Float16)p0, (_Float16)p1 };
      f16x2 w23 = { (_Float16)p2, (_Float16)p3 };
      *(f16x2*)&Pl[off] = w01;
      *(f16x2*)&Pl[off + 2] = w23;
    }
    ps += __shfl_xor(ps, 16);
    ps += __shfl_xor(ps, 32);
    l_run = l_run * fac + ps;
    m_run = mnew;
    #pragma unroll
    for (int r = 0; r < 4; ++r) {
      float fr = __shfl(fac, 4 * g + r);
      #pragma unroll
      for (int nt = 0; nt < 5; ++nt) ctxa[nt][r] *= fr;
    }
    #pragma unroll
    for (int kb4 = 0; kb4 < 2; ++kb4) {
      f16x8 pf = *(const f16x8*)&Pl[(w * 16 + ln) * 72 + kb4 * 32 + g * 8];
      #pragma unroll
      for (int nt = 0; nt < 5; ++nt) {
        f16x8 vf = *(const f16x8*)&Vl[(nt * 16 + ln) * 72 + kb4 * 32 + g * 8];
        ctxa[nt] = __builtin_amdgcn_mfma_f32_16x16x32_f16(pf, vf, ctxa[nt], 0, 0, 0);
      }
    }
  }
  #pragma unroll
  for (int r = 0; r < 4; ++r) {
    float lr = __shfl(l_run, 4 * g + r);
    float inv = 1.f / lr;
    int s = s0 + w * 16 + 4 * g + r;
    int base = (s * 8 + bb) * 1280 + h * 80;
    #pragma unroll
    for (int nt = 0; nt < 5; ++nt)
      ctxg[base + nt * 16 + ln] = (_Float16)(ctxa[nt][r] * inv);
  }
}

extern "C" void kernel_launch(void* const* d_in, const int* in_sizes, int n_in,
                              void* d_out, int out_size, void* d_ws, size_t ws_size,
                              hipStream_t stream) {
  const float* x     = (const float*)d_in[0];
  const float* w_in  = (const float*)d_in[1];
  const float* b_in  = (const float*)d_in[2];
  const float* w_out = (const float*)d_in[3];
  const float* b_out = (const float*)d_in[4];
  float* out = (float*)d_out;

  char* ws = (char*)d_ws;
  size_t off = 0;
  auto carve = [&](size_t bytes) -> void* {
    void* p = ws + off;
    off += (bytes + 255) & ~(size_t)255;
    return p;
  };
  _Float16* xb     = (_Float16*)carve(8192ull * 1280 * 2);
  _Float16* w_inT  = (_Float16*)carve(3840ull * 1280 * 2);
  _Float16* w_outT = (_Float16*)carve(1280ull * 1280 * 2);
  _Float16* qb     = (_Float16*)carve(128ull * 1024 * 96 * 2);
  _Float16* kbuf   = (_Float16*)carve(128ull * 1024 * 96 * 2);
  _Float16* vb     = (_Float16*)carve(128ull * 1024 * 80 * 2);
  _Float16* vT     = (_Float16*)carve(128ull * 1024 * 80 * 2);
  _Float16* ctxg   = (_Float16*)carve(8192ull * 1280 * 2);
  if (off > ws_size) return;

  hipFuncSetAttribute(reinterpret_cast<const void*>(&k_gemm8<8192, 3840, 1280, 1>),
                      hipFuncAttributeMaxDynamicSharedMemorySize, 131072);
  hipFuncSetAttribute(reinterpret_cast<const void*>(&k_gemm8<8192, 1280, 1280, 0>),
                      hipFuncAttributeMaxDynamicSharedMemorySize, 131072);

  hipMemsetAsync(qb, 0, 128ull * 1024 * 96 * 2, stream);
  hipMemsetAsync(kbuf, 0, 128ull * 1024 * 96 * 2, stream);

  k_cvt<<<2048, 256, 0, stream>>>(x, xb, 8192 * 1280 / 4);
  k_transpose<<<dim3(120, 40), 256, 0, stream>>>(w_in, w_inT, 1280, 3840);
  k_transpose<<<dim3(40, 40), 256, 0, stream>>>(w_out, w_outT, 1280, 1280);

  k_gemm8<8192, 3840, 1280, 1><<<480, 512, 131072, stream>>>(xb, w_inT, b_in, nullptr, qb, kbuf, vb);
  k_vtrans<<<2048, 256, 0, stream>>>(vb, vT);
  k_attn<<<2048, 256, 0, stream>>>(qb, kbuf, vT, ctxg);
  k_gemm8<8192, 1280, 1280, 0><<<160, 512, 131072, stream>>>(ctxg, w_outT, b_out, out, nullptr, nullptr, nullptr);
}

// Round 3
// 270.217 us; speedup vs baseline: 1.1889x; 1.1889x over previous
//
#include <hip/hip_runtime.h>

#define DEVI __device__ __forceinline__

typedef _Float16 f16x8 __attribute__((ext_vector_type(8)));
typedef _Float16 f16x4v __attribute__((ext_vector_type(4)));
typedef _Float16 f16x2 __attribute__((ext_vector_type(2)));
typedef float f32x4 __attribute__((ext_vector_type(4)));

DEVI void gl16(const void* g, void* l) {
  __builtin_amdgcn_global_load_lds((const __attribute__((address_space(1))) void*)g,
                                   (__attribute__((address_space(3))) void*)l, 16, 0, 0);
}

#define VMCNT(N) asm volatile("s_waitcnt vmcnt(" #N ")" ::: "memory")
#define LGKM0() asm volatile("s_waitcnt lgkmcnt(0)" ::: "memory")
#define BARRIER() asm volatile("s_barrier" ::: "memory")

// ---------------- f32 -> f16 convert ----------------
__global__ __launch_bounds__(256) void k_cvt(const float* __restrict__ in, _Float16* __restrict__ out, int n4) {
  int i = blockIdx.x * 256 + threadIdx.x;
  int stride = gridDim.x * 256;
  for (; i < n4; i += stride) {
    float4 v = ((const float4*)in)[i];
    f16x4v h = { (_Float16)v.x, (_Float16)v.y, (_Float16)v.z, (_Float16)v.w };
    ((f16x4v*)out)[i] = h;
  }
}

// ---------------- transpose + convert: in[R][C] f32 -> out[C][R] f16 ----------------
__global__ __launch_bounds__(256) void k_transpose(const float* __restrict__ in, _Float16* __restrict__ out,
                                                   int R, int C) {
  __shared__ float t[32][33];
  int cb = blockIdx.x * 32, rb = blockIdx.y * 32;
  int tx = threadIdx.x & 31, ty = threadIdx.x >> 5;
  #pragma unroll
  for (int i = ty; i < 32; i += 8) t[i][tx] = in[(size_t)(rb + i) * C + cb + tx];
  __syncthreads();
  #pragma unroll
  for (int i = ty; i < 32; i += 8) out[(size_t)(cb + i) * R + rb + tx] = (_Float16)t[tx][i];
}

// ================= 256x256 8-phase GEMM (qkv producer) =================
// C[M,N] = A[M,K] * BT[N,K]^T + bias; epilogue retiles through LDS and writes
// q/k/v as [head][1024][80] f16 with coalesced 16B stores (q pre-scaled by 1/sqrt(80)).

#define MM(NLO, AF, BF) do {                                                                       \
    __builtin_amdgcn_s_setprio(1);                                                                 \
    _Pragma("unroll")                                                                              \
    for (int m_ = 0; m_ < 8; m_++) {                                                               \
      acc[m_][NLO]     = __builtin_amdgcn_mfma_f32_16x16x32_f16(AF[m_], BF[NLO],     acc[m_][NLO],     0, 0, 0); \
      acc[m_][NLO + 1] = __builtin_amdgcn_mfma_f32_16x16x32_f16(AF[m_], BF[NLO + 1], acc[m_][NLO + 1], 0, 0, 0); \
    }                                                                                              \
    __builtin_amdgcn_s_setprio(0);                                                                 \
  } while (0)

#define LDA(KT, KK, DST) do {                                                                      \
    const _Float16* bas_ = &smem[(size_t)((((KT) & 1) * 2) + wr) * 8192];                          \
    _Pragma("unroll")                                                                              \
    for (int m_ = 0; m_ < 8; m_++)                                                                 \
      DST[m_] = *(const f16x8*)&bas_[(m_ * 16 + ln) * 64 + (((((KK) * 4) + g) ^ chB) << 3)];       \
  } while (0)

#define LDB(KT, KK, DST) do {                                                                      \
    const _Float16* bas_ = &smem[32768 + (size_t)((((KT) & 1) * 2) + (wc >> 1)) * 8192];           \
    _Pragma("unroll")                                                                              \
    for (int n_ = 0; n_ < 4; n_++)                                                                 \
      DST[n_] = *(const f16x8*)&bas_[((wc & 1) * 64 + n_ * 16 + ln) * 64 + (((((KK) * 4) + g) ^ chB) << 3)]; \
  } while (0)

template<int M, int N, int K>
__global__ __launch_bounds__(512, 2) void k_gemm8(const _Float16* __restrict__ A, const _Float16* __restrict__ BT,
                                                  const float* __restrict__ bias,
                                                  _Float16* __restrict__ qo, _Float16* __restrict__ ko,
                                                  _Float16* __restrict__ vo) {
  extern __shared__ _Float16 smem[];  // [0,32768): A   [32768,65536): B   (f16 counts)
  constexpr int NT = K / 64;
  constexpr int NI = NT / 2;
  const int tid = threadIdx.x;
  const int w = tid >> 6, lane = tid & 63, ln = lane & 15, g = lane >> 4;
  const int wr = w >> 2, wc = w & 3;
  const int l8 = lane >> 3, l7 = lane & 7;
  const int stChunk = (l7 ^ l8) << 3;
  const int chB = ln & 7;

  // M-band XCD mapping: xcd owns M-tiles [xcd*4, xcd*4+4), sweeps N
  constexpr int MT = M / 256;             // 32
  const int xcd = blockIdx.x & 7;
  const int i = blockIdx.x >> 3;          // 0..59
  const int bm0 = (xcd * (MT / 8) + (i & 3)) * 256;
  const int bn0 = (i >> 2) * 256;

  auto stgA = [&](int kt, int hh) {
    _Float16* ldsb = &smem[(size_t)((kt & 1) * 2 + hh) * 8192 + w * 1024];
    const _Float16* g0 = &A[(size_t)(bm0 + hh * 128 + w * 16 + l8) * K + kt * 64 + stChunk];
    gl16(g0, ldsb);
    gl16(g0 + (size_t)8 * K, ldsb + 512);
  };
  auto stgB = [&](int kt, int hh) {
    _Float16* ldsb = &smem[32768 + (size_t)((kt & 1) * 2 + hh) * 8192 + w * 1024];
    const _Float16* g0 = &BT[(size_t)(bn0 + hh * 128 + w * 16 + l8) * K + kt * 64 + stChunk];
    gl16(g0, ldsb);
    gl16(g0 + (size_t)8 * K, ldsb + 512);
  };

  f32x4 acc[8][4] = {};
  f16x8 a0[8], a1[8], b0[4], b1[4];

  stgB(0, 0); stgB(0, 1); stgA(0, 0); stgA(0, 1);
  stgB(1, 0); stgB(1, 1); stgA(1, 0);
  VMCNT(6);
  BARRIER();
  LDA(0, 0, a0); LDB(0, 0, b0);

  for (int it = 0; it < NI; ++it) {
    const int T0 = 2 * it, T1 = 2 * it + 1;
    const int S0 = (T0 + 2 < NT) ? T0 + 2 : 0;  // wrap keeps parity; wrapped data never read
    const int S1 = (T1 + 2 < NT) ? T1 + 2 : 1;
    // ph1
    LDB(T0, 1, b1);
    stgA(T1, 1);
    BARRIER();
    MM(0, a0, b0);
    LGKM0(); BARRIER();
    // ph2
    LDA(T0, 1, a1);
    stgB(S0, 0);
    BARRIER();
    MM(2, a0, b0);
    LGKM0(); BARRIER();
    // ph3
    stgB(S0, 1);
    BARRIER();
    MM(0, a1, b1);
    VMCNT(4);
    LGKM0(); BARRIER();
    // ph4
    LDA(T1, 0, a0); LDB(T1, 0, b0);
    stgA(S0, 0);
    BARRIER();
    MM(2, a1, b1);
    LGKM0(); BARRIER();
    // ph5
    LDB(T1, 1, b1);
    stgA(S0, 1);
    BARRIER();
    MM(0, a0, b0);
    LGKM0(); BARRIER();
    // ph6
    LDA(T1, 1, a1);
    stgB(S1, 0);
    BARRIER();
    MM(2, a0, b0);
    LGKM0(); BARRIER();
    // ph7
    stgB(S1, 1);
    BARRIER();
    MM(0, a1, b1);
    VMCNT(4);
    LGKM0(); BARRIER();
    // ph8
    LDA(S0, 0, a0); LDB(S0, 0, b0);
    stgA(S1, 0);
    BARRIER();
    MM(2, a1, b1);
    LGKM0(); BARRIER();
  }

  // ---- epilogue: acc -> LDS f16 [256][256] -> coalesced 16B q/k/v stores ----
  VMCNT(0);      // drain wrapped tail stages before reusing smem
  BARRIER();
  _Float16* sH = smem;
  #pragma unroll
  for (int n = 0; n < 4; n++) {
    int col = wc * 64 + n * 16 + ln;
    int gcol = bn0 + col;
    float bv = bias[gcol];
    int hq = gcol / 240;
    int tt = gcol - hq * 240;
    float scl = (tt < 80) ? 0.11180339887498948f : 1.0f;
    #pragma unroll
    for (int m = 0; m < 8; m++) {
      #pragma unroll
      for (int r = 0; r < 4; r++) {
        int row = wr * 128 + m * 16 + 4 * g + r;
        sH[row * 256 + col] = (_Float16)((acc[m][n][r] + bv) * scl);
      }
    }
  }
  LGKM0();
  BARRIER();
  #pragma unroll
  for (int i2 = 0; i2 < 16; i2++) {
    int id = tid + 512 * i2;
    int row = id >> 5, c8 = id & 31;
    f16x8 v = *(const f16x8*)&sH[row * 256 + c8 * 8];
    int gcol = bn0 + c8 * 8;
    int grow = bm0 + row;
    int hq = gcol / 240;
    int tt = gcol - hq * 240;
    int reg = tt / 80;
    int cc = tt - reg * 80;
    int s = grow >> 3;
    int head = (grow & 7) * 16 + hq;
    _Float16* dst = (reg == 0) ? qo : (reg == 1) ? ko : vo;
    *(f16x8*)&dst[(size_t)(head * 1024 + s) * 80 + cc] = v;
  }
}

// ---------------- 128x128 GEMM (out_proj): C[M,N] = A[M,K]*BT[N,K]^T + bias, f32 out ----
template<int M, int N, int K>
__global__ __launch_bounds__(256) void k_gemm(const _Float16* __restrict__ A, const _Float16* __restrict__ BT,
                                              const float* __restrict__ bias, float* __restrict__ outF) {
  __shared__ _Float16 Al[128 * 32];
  __shared__ _Float16 Bl[128 * 32];
  const int tid = threadIdx.x;
  const int w = tid >> 6, lane = tid & 63, ln = lane & 15, g = lane >> 4;
  const int bm0 = blockIdx.x * 128, bn0 = blockIdx.y * 128;
  const int wm = (w >> 1) * 64, wn = (w & 1) * 64;
  const int r0 = tid >> 2, c0 = (tid & 3) * 8;
  f32x4 acc[4][4] = {};
  for (int kt = 0; kt < K; kt += 32) {
    __syncthreads();
    gl16(&A[(size_t)(bm0 + r0) * K + kt + c0],      &Al[(w * 64) * 8]);
    gl16(&A[(size_t)(bm0 + r0 + 64) * K + kt + c0], &Al[(256 + w * 64) * 8]);
    gl16(&BT[(size_t)(bn0 + r0) * K + kt + c0],      &Bl[(w * 64) * 8]);
    gl16(&BT[(size_t)(bn0 + r0 + 64) * K + kt + c0], &Bl[(256 + w * 64) * 8]);
    __syncthreads();
    f16x8 af[4], bf[4];
    #pragma unroll
    for (int i = 0; i < 4; i++) af[i] = *(const f16x8*)&Al[(wm + i * 16 + ln) * 32 + g * 8];
    #pragma unroll
    for (int i = 0; i < 4; i++) bf[i] = *(const f16x8*)&Bl[(wn + i * 16 + ln) * 32 + g * 8];
    #pragma unroll
    for (int i = 0; i < 4; i++)
      #pragma unroll
      for (int j = 0; j < 4; j++)
        acc[i][j] = __builtin_amdgcn_mfma_f32_16x16x32_f16(af[i], bf[j], acc[i][j], 0, 0, 0);
  }
  #pragma unroll
  for (int j = 0; j < 4; j++) {
    int col = bn0 + wn + j * 16 + ln;
    float bv = bias[col];
    #pragma unroll
    for (int i = 0; i < 4; i++) {
      int mb = bm0 + wm + i * 16 + 4 * g;
      #pragma unroll
      for (int r = 0; r < 4; r++)
        outF[(size_t)(mb + r) * N + col] = acc[i][j][r] + bv;
    }
  }
}

// ---------------- per-head V transpose: vb[head][1024][80] -> vT[head][80][1024] ----------------
__global__ __launch_bounds__(256) void k_vtrans(const _Float16* __restrict__ vb, _Float16* __restrict__ vT) {
  __shared__ _Float16 t[64][81];
  int head = blockIdx.x >> 4;
  int sb = (blockIdx.x & 15) * 64;
  for (int idx = threadIdx.x; idx < 64 * 80; idx += 256) {
    int s = idx / 80, d = idx - s * 80;
    t[s][d] = vb[(head * 1024 + sb + s) * 80 + d];
  }
  __syncthreads();
  for (int idx = threadIdx.x; idx < 80 * 64; idx += 256) {
    int d = idx >> 6, s = idx & 63;
    vT[(head * 80 + d) * 1024 + sb + s] = t[s][d];
  }
}

// ---------------- flash attention (QBLK=128, 8 waves, XCD-pinned heads) ----------------
// qb/kb: [head][1024][80] f16 (q pre-scaled), vT: [head][80][1024]
// ctxg: [s][b][h*80+d] f16 == [8192][1280]
__global__ __launch_bounds__(512) void k_attn(const _Float16* __restrict__ qb, const _Float16* __restrict__ kb,
                                              const _Float16* __restrict__ vT, _Float16* __restrict__ ctxg) {
  __shared__ _Float16 Kl[64 * 104];   // cols 80..95 zeroed (QK pad), stride 104
  __shared__ _Float16 Vl[80 * 72];
  __shared__ _Float16 Pl[128 * 72];
  const int tid = threadIdx.x;
  const int w = tid >> 6, lane = tid & 63, ln = lane & 15, g = lane >> 4;
  // XCD-pinned mapping: all 8 q-tiles + 16 heads per XCD
  const int xcd = blockIdx.x & 7;
  const int j = blockIdx.x >> 3;            // 0..127
  const int head = xcd + 8 * (j & 15);
  const int s0 = (j >> 4) * 128;
  const int bb = head >> 4, h = head & 15;

  const int qrow = s0 + w * 16 + ln;
  f16x8 qf[3];
  qf[0] = *(const f16x8*)&qb[(size_t)(head * 1024 + qrow) * 80 + g * 8];
  qf[1] = *(const f16x8*)&qb[(size_t)(head * 1024 + qrow) * 80 + 32 + g * 8];
  {
    f16x8 z = {};
    qf[2] = (g < 2) ? *(const f16x8*)&qb[(size_t)(head * 1024 + qrow) * 80 + 64 + g * 8] : z;
  }

  f32x4 ctxa[5] = {};
  float m_run = -INFINITY, l_run = 0.f;

  for (int kt2 = 0; kt2 < 16; ++kt2) {
    __syncthreads();
    // stage K tile [64][80] -> Kl[64][104], chunks 10..12 zero
    for (int c = tid; c < 832; c += 512) {
      int row = c / 13, ch = c - row * 13;
      uint4 z4 = {0, 0, 0, 0};
      uint4 v4 = (ch < 10) ? *(const uint4*)&kb[(size_t)(head * 1024 + kt2 * 64 + row) * 80 + ch * 8] : z4;
      *(uint4*)&Kl[row * 104 + ch * 8] = v4;
    }
    // stage V^T tile [80][64] -> Vl (stride 72)
    for (int c = tid; c < 640; c += 512) {
      int row = c >> 3, ch = c & 7;
      *(uint4*)&Vl[row * 72 + ch * 8] = *(const uint4*)&vT[(size_t)(head * 80 + row) * 1024 + kt2 * 64 + ch * 8];
    }
    __syncthreads();
    // T = K * Q^T : sc[t16] rows kk = t16*16+4g+r, col q = ln (per wave)
    f32x4 sc[4] = {};
    #pragma unroll
    for (int t16 = 0; t16 < 4; ++t16)
      #pragma unroll
      for (int dc = 0; dc < 3; ++dc) {
        f16x8 kf = *(const f16x8*)&Kl[(t16 * 16 + ln) * 104 + dc * 32 + g * 8];
        sc[t16] = __builtin_amdgcn_mfma_f32_16x16x32_f16(kf, qf[dc], sc[t16], 0, 0, 0);
      }
    // online softmax (per-lane col q = ln, 4 lane-groups partition kk)
    float tm = -INFINITY;
    #pragma unroll
    for (int t16 = 0; t16 < 4; ++t16)
      #pragma unroll
      for (int r = 0; r < 4; ++r) tm = fmaxf(tm, sc[t16][r]);
    tm = fmaxf(tm, __shfl_xor(tm, 16));
    tm = fmaxf(tm, __shfl_xor(tm, 32));
    float mnew = fmaxf(m_run, tm);
    float fac = __expf(m_run - mnew);
    float ps = 0.f;
    #pragma unroll
    for (int t16 = 0; t16 < 4; ++t16) {
      float p0 = __expf(sc[t16][0] - mnew);
      float p1 = __expf(sc[t16][1] - mnew);
      float p2 = __expf(sc[t16][2] - mnew);
      float p3 = __expf(sc[t16][3] - mnew);
      ps += (p0 + p1) + (p2 + p3);
      int off = (w * 16 + ln) * 72 + t16 * 16 + g * 4;
      f16x2 w01 = { (_Float16)p0, (_Float16)p1 };
      f16x2 w23 = { (_Float16)p2, (_Float16)p3 };
      *(f16x2*)&Pl[off] = w01;
      *(f16x2*)&Pl[off + 2] = w23;
    }
    ps += __shfl_xor(ps, 16);
    ps += __shfl_xor(ps, 32);
    l_run = l_run * fac + ps;
    m_run = mnew;
    #pragma unroll
    for (int r = 0; r < 4; ++r) {
      float fr = __shfl(fac, 4 * g + r);
      #pragma unroll
      for (int nt = 0; nt < 5; ++nt) ctxa[nt][r] *= fr;
    }
    // PV: ctx[q][d] += P[q][kk] * V[kk][d]
    #pragma unroll
    for (int kb4 = 0; kb4 < 2; ++kb4) {
      f16x8 pf = *(const f16x8*)&Pl[(w * 16 + ln) * 72 + kb4 * 32 + g * 8];
      #pragma unroll
      for (int nt = 0; nt < 5; ++nt) {
        f16x8 vf = *(const f16x8*)&Vl[(nt * 16 + ln) * 72 + kb4 * 32 + g * 8];
        ctxa[nt] = __builtin_amdgcn_mfma_f32_16x16x32_f16(pf, vf, ctxa[nt], 0, 0, 0);
      }
    }
  }
  // epilogue
  #pragma unroll
  for (int r = 0; r < 4; ++r) {
    float lr = __shfl(l_run, 4 * g + r);
    float inv = 1.f / lr;
    int s = s0 + w * 16 + 4 * g + r;
    int base = (s * 8 + bb) * 1280 + h * 80;
    #pragma unroll
    for (int nt = 0; nt < 5; ++nt)
      ctxg[base + nt * 16 + ln] = (_Float16)(ctxa[nt][r] * inv);
  }
}

extern "C" void kernel_launch(void* const* d_in, const int* in_sizes, int n_in,
                              void* d_out, int out_size, void* d_ws, size_t ws_size,
                              hipStream_t stream) {
  const float* x     = (const float*)d_in[0];
  const float* w_in  = (const float*)d_in[1];
  const float* b_in  = (const float*)d_in[2];
  const float* w_out = (const float*)d_in[3];
  const float* b_out = (const float*)d_in[4];
  float* out = (float*)d_out;

  char* ws = (char*)d_ws;
  size_t off = 0;
  auto carve = [&](size_t bytes) -> void* {
    void* p = ws + off;
    off += (bytes + 255) & ~(size_t)255;
    return p;
  };
  _Float16* xb     = (_Float16*)carve(8192ull * 1280 * 2);
  _Float16* w_inT  = (_Float16*)carve(3840ull * 1280 * 2);
  _Float16* w_outT = (_Float16*)carve(1280ull * 1280 * 2);
  _Float16* qb     = (_Float16*)carve(128ull * 1024 * 80 * 2);
  _Float16* kbuf   = (_Float16*)carve(128ull * 1024 * 80 * 2);
  _Float16* vb     = (_Float16*)carve(128ull * 1024 * 80 * 2);
  _Float16* vT     = (_Float16*)carve(128ull * 1024 * 80 * 2);
  _Float16* ctxg   = (_Float16*)carve(8192ull * 1280 * 2);
  if (off > ws_size) return;

  hipFuncSetAttribute(reinterpret_cast<const void*>(&k_gemm8<8192, 3840, 1280>),
                      hipFuncAttributeMaxDynamicSharedMemorySize, 131072);

  k_cvt<<<2048, 256, 0, stream>>>(x, xb, 8192 * 1280 / 4);
  k_transpose<<<dim3(120, 40), 256, 0, stream>>>(w_in, w_inT, 1280, 3840);
  k_transpose<<<dim3(40, 40), 256, 0, stream>>>(w_out, w_outT, 1280, 1280);

  k_gemm8<8192, 3840, 1280><<<480, 512, 131072, stream>>>(xb, w_inT, b_in, qb, kbuf, vb);
  k_vtrans<<<2048, 256, 0, stream>>>(vb, vT);
  k_attn<<<1024, 512, 0, stream>>>(qb, kbuf, vT, ctxg);
  k_gemm<8192, 1280, 1280><<<dim3(64, 10), 256, 0, stream>>>(ctxg, w_outT, b_out, out);
}

// Round 5
// 266.861 us; speedup vs baseline: 1.2039x; 1.0126x over previous
//
#include <hip/hip_runtime.h>

#define DEVI __device__ __forceinline__

typedef _Float16 f16x8 __attribute__((ext_vector_type(8)));
typedef _Float16 f16x4v __attribute__((ext_vector_type(4)));
typedef _Float16 f16x2 __attribute__((ext_vector_type(2)));
typedef __fp16 fp16x2 __attribute__((ext_vector_type(2)));
typedef float f32x4 __attribute__((ext_vector_type(4)));
typedef float f32x16 __attribute__((ext_vector_type(16)));

DEVI void gl16(const void* g, void* l) {
  __builtin_amdgcn_global_load_lds((const __attribute__((address_space(1))) void*)g,
                                   (__attribute__((address_space(3))) void*)l, 16, 0, 0);
}

#define VMCNT(N) asm volatile("s_waitcnt vmcnt(" #N ")" ::: "memory")
#define LGKM0() asm volatile("s_waitcnt lgkmcnt(0)" ::: "memory")
#define BARRIER() asm volatile("s_barrier" ::: "memory")

DEVI unsigned pk2(float a, float b) {
  fp16x2 t = __builtin_amdgcn_cvt_pkrtz(a, b);
  return __builtin_bit_cast(unsigned, t);
}

// ---------------- f32 -> f16 convert ----------------
__global__ __launch_bounds__(256) void k_cvt(const float* __restrict__ in, _Float16* __restrict__ out, int n4) {
  int i = blockIdx.x * 256 + threadIdx.x;
  int stride = gridDim.x * 256;
  for (; i < n4; i += stride) {
    float4 v = ((const float4*)in)[i];
    f16x4v h = { (_Float16)v.x, (_Float16)v.y, (_Float16)v.z, (_Float16)v.w };
    ((f16x4v*)out)[i] = h;
  }
}

// ---------------- transpose + convert: in[R][C] f32 -> out[C][R] f16 ----------------
__global__ __launch_bounds__(256) void k_transpose(const float* __restrict__ in, _Float16* __restrict__ out,
                                                   int R, int C) {
  __shared__ float t[32][33];
  int cb = blockIdx.x * 32, rb = blockIdx.y * 32;
  int tx = threadIdx.x & 31, ty = threadIdx.x >> 5;
  #pragma unroll
  for (int i = ty; i < 32; i += 8) t[i][tx] = in[(size_t)(rb + i) * C + cb + tx];
  __syncthreads();
  #pragma unroll
  for (int i = ty; i < 32; i += 8) out[(size_t)(cb + i) * R + rb + tx] = (_Float16)t[tx][i];
}

// ================= 256x256 8-phase GEMM (qkv producer) =================

#define MM(NLO, AF, BF) do {                                                                       \
    __builtin_amdgcn_s_setprio(1);                                                                 \
    _Pragma("unroll")                                                                              \
    for (int m_ = 0; m_ < 8; m_++) {                                                               \
      acc[m_][NLO]     = __builtin_amdgcn_mfma_f32_16x16x32_f16(AF[m_], BF[NLO],     acc[m_][NLO],     0, 0, 0); \
      acc[m_][NLO + 1] = __builtin_amdgcn_mfma_f32_16x16x32_f16(AF[m_], BF[NLO + 1], acc[m_][NLO + 1], 0, 0, 0); \
    }                                                                                              \
    __builtin_amdgcn_s_setprio(0);                                                                 \
  } while (0)

#define LDA(KT, KK, DST) do {                                                                      \
    const _Float16* bas_ = &smem[(size_t)((((KT) & 1) * 2) + wr) * 8192];                          \
    _Pragma("unroll")                                                                              \
    for (int m_ = 0; m_ < 8; m_++)                                                                 \
      DST[m_] = *(const f16x8*)&bas_[(m_ * 16 + ln) * 64 + (((((KK) * 4) + g) ^ chB) << 3)];       \
  } while (0)

#define LDB(KT, KK, DST) do {                                                                      \
    const _Float16* bas_ = &smem[32768 + (size_t)((((KT) & 1) * 2) + (wc >> 1)) * 8192];           \
    _Pragma("unroll")                                                                              \
    for (int n_ = 0; n_ < 4; n_++)                                                                 \
      DST[n_] = *(const f16x8*)&bas_[((wc & 1) * 64 + n_ * 16 + ln) * 64 + (((((KK) * 4) + g) ^ chB) << 3)]; \
  } while (0)

template<int M, int N, int K>
__global__ __launch_bounds__(512, 2) void k_gemm8(const _Float16* __restrict__ A, const _Float16* __restrict__ BT,
                                                  const float* __restrict__ bias,
                                                  _Float16* __restrict__ qo, _Float16* __restrict__ ko,
                                                  _Float16* __restrict__ vo) {
  extern __shared__ _Float16 smem[];
  constexpr int NT = K / 64;
  constexpr int NI = NT / 2;
  const int tid = threadIdx.x;
  const int w = tid >> 6, lane = tid & 63, ln = lane & 15, g = lane >> 4;
  const int wr = w >> 2, wc = w & 3;
  const int l8 = lane >> 3, l7 = lane & 7;
  const int stChunk = (l7 ^ l8) << 3;
  const int chB = ln & 7;

  constexpr int MT = M / 256;
  const int xcd = blockIdx.x & 7;
  const int i = blockIdx.x >> 3;
  const int bm0 = (xcd * (MT / 8) + (i & 3)) * 256;
  const int bn0 = (i >> 2) * 256;

  auto stgA = [&](int kt, int hh) {
    _Float16* ldsb = &smem[(size_t)((kt & 1) * 2 + hh) * 8192 + w * 1024];
    const _Float16* g0 = &A[(size_t)(bm0 + hh * 128 + w * 16 + l8) * K + kt * 64 + stChunk];
    gl16(g0, ldsb);
    gl16(g0 + (size_t)8 * K, ldsb + 512);
  };
  auto stgB = [&](int kt, int hh) {
    _Float16* ldsb = &smem[32768 + (size_t)((kt & 1) * 2 + hh) * 8192 + w * 1024];
    const _Float16* g0 = &BT[(size_t)(bn0 + hh * 128 + w * 16 + l8) * K + kt * 64 + stChunk];
    gl16(g0, ldsb);
    gl16(g0 + (size_t)8 * K, ldsb + 512);
  };

  f32x4 acc[8][4] = {};
  f16x8 a0[8], a1[8], b0[4], b1[4];

  stgB(0, 0); stgB(0, 1); stgA(0, 0); stgA(0, 1);
  stgB(1, 0); stgB(1, 1); stgA(1, 0);
  VMCNT(6);
  BARRIER();
  LDA(0, 0, a0); LDB(0, 0, b0);

  for (int it = 0; it < NI; ++it) {
    const int T0 = 2 * it, T1 = 2 * it + 1;
    const int S0 = (T0 + 2 < NT) ? T0 + 2 : 0;
    const int S1 = (T1 + 2 < NT) ? T1 + 2 : 1;
    LDB(T0, 1, b1);
    stgA(T1, 1);
    BARRIER();
    MM(0, a0, b0);
    LGKM0(); BARRIER();
    LDA(T0, 1, a1);
    stgB(S0, 0);
    BARRIER();
    MM(2, a0, b0);
    LGKM0(); BARRIER();
    stgB(S0, 1);
    BARRIER();
    MM(0, a1, b1);
    VMCNT(4);
    LGKM0(); BARRIER();
    LDA(T1, 0, a0); LDB(T1, 0, b0);
    stgA(S0, 0);
    BARRIER();
    MM(2, a1, b1);
    LGKM0(); BARRIER();
    LDB(T1, 1, b1);
    stgA(S0, 1);
    BARRIER();
    MM(0, a0, b0);
    LGKM0(); BARRIER();
    LDA(T1, 1, a1);
    stgB(S1, 0);
    BARRIER();
    MM(2, a0, b0);
    LGKM0(); BARRIER();
    stgB(S1, 1);
    BARRIER();
    MM(0, a1, b1);
    VMCNT(4);
    LGKM0(); BARRIER();
    LDA(S0, 0, a0); LDB(S0, 0, b0);
    stgA(S1, 0);
    BARRIER();
    MM(2, a1, b1);
    LGKM0(); BARRIER();
  }

  // epilogue: acc -> LDS f16 [256][256] -> coalesced 16B q/k/v stores
  VMCNT(0);
  BARRIER();
  _Float16* sH = smem;
  #pragma unroll
  for (int n = 0; n < 4; n++) {
    int col = wc * 64 + n * 16 + ln;
    int gcol = bn0 + col;
    float bv = bias[gcol];
    int hq = gcol / 240;
    int tt = gcol - hq * 240;
    // q gets 1/sqrt(80) * log2(e) so attention works in exp2 domain
    float scl = (tt < 80) ? (0.11180339887498948f * 1.4426950408889634f) : 1.0f;
    #pragma unroll
    for (int m = 0; m < 8; m++) {
      #pragma unroll
      for (int r = 0; r < 4; r++) {
        int row = wr * 128 + m * 16 + 4 * g + r;
        sH[row * 256 + col] = (_Float16)((acc[m][n][r] + bv) * scl);
      }
    }
  }
  LGKM0();
  BARRIER();
  #pragma unroll
  for (int i2 = 0; i2 < 16; i2++) {
    int id = tid + 512 * i2;
    int row = id >> 5, c8 = id & 31;
    f16x8 v = *(const f16x8*)&sH[row * 256 + c8 * 8];
    int gcol = bn0 + c8 * 8;
    int grow = bm0 + row;
    int hq = gcol / 240;
    int tt = gcol - hq * 240;
    int reg = tt / 80;
    int cc = tt - reg * 80;
    int s = grow >> 3;
    int head = (grow & 7) * 16 + hq;
    _Float16* dst = (reg == 0) ? qo : (reg == 1) ? ko : vo;
    *(f16x8*)&dst[(size_t)(head * 1024 + s) * 80 + cc] = v;
  }
}

// ---------------- 128x128 GEMM (out_proj) ----------------
template<int M, int N, int K>
__global__ __launch_bounds__(256) void k_gemm(const _Float16* __restrict__ A, const _Float16* __restrict__ BT,
                                              const float* __restrict__ bias, float* __restrict__ outF) {
  __shared__ _Float16 Al[128 * 32];
  __shared__ _Float16 Bl[128 * 32];
  const int tid = threadIdx.x;
  const int w = tid >> 6, lane = tid & 63, ln = lane & 15, g = lane >> 4;
  const int bm0 = blockIdx.x * 128, bn0 = blockIdx.y * 128;
  const int wm = (w >> 1) * 64, wn = (w & 1) * 64;
  const int r0 = tid >> 2, c0 = (tid & 3) * 8;
  f32x4 acc[4][4] = {};
  for (int kt = 0; kt < K; kt += 32) {
    __syncthreads();
    gl16(&A[(size_t)(bm0 + r0) * K + kt + c0],      &Al[(w * 64) * 8]);
    gl16(&A[(size_t)(bm0 + r0 + 64) * K + kt + c0], &Al[(256 + w * 64) * 8]);
    gl16(&BT[(size_t)(bn0 + r0) * K + kt + c0],      &Bl[(w * 64) * 8]);
    gl16(&BT[(size_t)(bn0 + r0 + 64) * K + kt + c0], &Bl[(256 + w * 64) * 8]);
    __syncthreads();
    f16x8 af[4], bf[4];
    #pragma unroll
    for (int i = 0; i < 4; i++) af[i] = *(const f16x8*)&Al[(wm + i * 16 + ln) * 32 + g * 8];
    #pragma unroll
    for (int i = 0; i < 4; i++) bf[i] = *(const f16x8*)&Bl[(wn + i * 16 + ln) * 32 + g * 8];
    #pragma unroll
    for (int i = 0; i < 4; i++)
      #pragma unroll
      for (int j = 0; j < 4; j++)
        acc[i][j] = __builtin_amdgcn_mfma_f32_16x16x32_f16(af[i], bf[j], acc[i][j], 0, 0, 0);
  }
  #pragma unroll
  for (int j = 0; j < 4; j++) {
    int col = bn0 + wn + j * 16 + ln;
    float bv = bias[col];
    #pragma unroll
    for (int i = 0; i < 4; i++) {
      int mb = bm0 + wm + i * 16 + 4 * g;
      #pragma unroll
      for (int r = 0; r < 4; r++)
        outF[(size_t)(mb + r) * N + col] = acc[i][j][r] + bv;
    }
  }
}

// ---------------- per-head V transpose ----------------
__global__ __launch_bounds__(256) void k_vtrans(const _Float16* __restrict__ vb, _Float16* __restrict__ vT) {
  __shared__ _Float16 t[64][81];
  int head = blockIdx.x >> 4;
  int sb = (blockIdx.x & 15) * 64;
  for (int idx = threadIdx.x; idx < 64 * 80; idx += 256) {
    int s = idx / 80, d = idx - s * 80;
    t[s][d] = vb[(head * 1024 + sb + s) * 80 + d];
  }
  __syncthreads();
  for (int idx = threadIdx.x; idx < 80 * 64; idx += 256) {
    int d = idx >> 6, s = idx & 63;
    vT[(head * 80 + d) * 1024 + sb + s] = t[s][d];
  }
}

// ---------------- flash attention: QBLK=256, 8 waves x 32 q-rows ----------------
// qb/kb: [head][1024][80] f16 (q pre-scaled by log2e/sqrt(80)), vT: [head][80][1024]
// QK via mfma 32x32x16 (K=80 = 5x16 exact); PV via 16x16x32.
// LDS: K [64][88] single-buf, V 2x[80][72] dbuf, P [256][88] wave-private rows.
__global__ __launch_bounds__(512, 4) void k_attn(const _Float16* __restrict__ qb, const _Float16* __restrict__ kb,
                                                 const _Float16* __restrict__ vT, _Float16* __restrict__ ctxg) {
  extern __shared__ _Float16 smem[];
  _Float16* Kb  = smem;                    // 64*88  = 5632 f16, stride 88
  _Float16* Vb0 = smem + 5632;             // 80*72  = 5760 f16, stride 72
  _Float16* Vb1 = smem + 5632 + 5760;
  _Float16* Pb  = smem + 5632 + 11520;     // 256*88 = 22528 f16, stride 88

  const int tid = threadIdx.x;
  const int w = tid >> 6, lane = tid & 63;
  const int ln = lane & 15, g = (lane >> 4) & 3;   // 16x16 roles (PV)
  const int l32 = lane & 31, h = lane >> 5;        // 32x32 roles (QK)
  const int xcd = blockIdx.x & 7;
  const int j = blockIdx.x >> 3;
  const int head = xcd + 8 * (j & 15);
  const int s0 = (j >> 4) * 256;
  const int bb = head >> 4, h16 = head & 15;

  // staging assignment: K tile 64x10 chunks (640), V tile 80x8 chunks (640); 2+2 per thread
  const int kc1 = (tid < 128) ? tid + 512 : tid;
  const int kr0 = tid / 10, kh0 = tid - kr0 * 10;
  const int kr1 = kc1 / 10, kh1 = kc1 - kr1 * 10;
  const int vr0 = tid >> 3, vh0 = tid & 7;
  const int vr1 = kc1 >> 3, vh1 = kc1 & 7;
  const size_t kbase = (size_t)head * 1024 * 80;
  const size_t vbase = (size_t)head * 80 * 1024;

  uint4 krA, krB, vrA, vrB;
  auto issue = [&](int kt) {
    const _Float16* kg = kb + kbase + (size_t)(kt * 64) * 80;
    krA = *(const uint4*)(kg + kr0 * 80 + kh0 * 8);
    krB = *(const uint4*)(kg + kr1 * 80 + kh1 * 8);
    const _Float16* vg = vT + vbase + kt * 64;
    vrA = *(const uint4*)(vg + (size_t)vr0 * 1024 + vh0 * 8);
    vrB = *(const uint4*)(vg + (size_t)vr1 * 1024 + vh1 * 8);
  };
  auto stage = [&](int kt) {
    *(uint4*)(Kb + kr0 * 88 + kh0 * 8) = krA;
    *(uint4*)(Kb + kr1 * 88 + kh1 * 8) = krB;
    _Float16* vd = (kt & 1) ? Vb1 : Vb0;
    *(uint4*)(vd + vr0 * 72 + vh0 * 8) = vrA;
    *(uint4*)(vd + vr1 * 72 + vh1 * 8) = vrB;
  };

  // Q fragments (B-operand of 32x32x16): col = q = l32, k = h*8+j per 16-slice
  const int qrow = s0 + w * 32 + l32;
  f16x8 qf[5];
  #pragma unroll
  for (int s = 0; s < 5; s++)
    qf[s] = *(const f16x8*)&qb[(size_t)(head * 1024 + qrow) * 80 + s * 16 + h * 8];

  f32x4 ctxa[2][5] = {};
  float m_run = -INFINITY, l_run = 0.f;

  issue(0);
  stage(0);          // compiler inserts counted vmcnt before these uses
  LGKM0();
  BARRIER();
  issue(1);

  for (int kt = 0; kt < 16; ++kt) {
    // ---- QK: sc[t][reg] = S[kk = t*32 + (reg&3)+8*(reg>>2)+4*h][q = l32] ----
    f32x16 sc[2] = {};
    __builtin_amdgcn_s_setprio(1);
    #pragma unroll
    for (int t = 0; t < 2; ++t)
      #pragma unroll
      for (int s = 0; s < 5; ++s) {
        f16x8 kf = *(const f16x8*)&Kb[(t * 32 + l32) * 88 + s * 16 + h * 8];
        sc[t] = __builtin_amdgcn_mfma_f32_32x32x16_f16(kf, qf[s], sc[t], 0, 0, 0);
      }
    __builtin_amdgcn_s_setprio(0);
    BARRIER();   // A: all waves done reading Kb

    // ---- online softmax (exp2 domain), per-lane column q = l32 ----
    float tm = -INFINITY;
    #pragma unroll
    for (int t = 0; t < 2; ++t)
      #pragma unroll
      for (int r = 0; r < 16; ++r) tm = fmaxf(tm, sc[t][r]);
    tm = fmaxf(tm, __shfl_xor(tm, 32));
    float mnew = fmaxf(m_run, tm);
    float fac = exp2f(m_run - mnew);
    float ps = 0.f;
    const int prow = (w * 32 + l32) * 88;
    #pragma unroll
    for (int t = 0; t < 2; ++t)
      #pragma unroll
      for (int rq = 0; rq < 4; ++rq) {
        float p0 = exp2f(sc[t][rq * 4 + 0] - mnew);
        float p1 = exp2f(sc[t][rq * 4 + 1] - mnew);
        float p2 = exp2f(sc[t][rq * 4 + 2] - mnew);
        float p3 = exp2f(sc[t][rq * 4 + 3] - mnew);
        ps += (p0 + p1) + (p2 + p3);
        unsigned long long u = (unsigned long long)pk2(p0, p1) | ((unsigned long long)pk2(p2, p3) << 32);
        *(unsigned long long*)&Pb[prow + t * 32 + rq * 8 + h * 4] = u;
      }
    ps += __shfl_xor(ps, 32);
    l_run = l_run * fac + ps;
    m_run = mnew;
    // rescale ctx accumulators (rows q = rb*16 + 4g + r)
    #pragma unroll
    for (int rb = 0; rb < 2; ++rb)
      #pragma unroll
      for (int r = 0; r < 4; ++r) {
        float fr = __shfl(fac, rb * 16 + 4 * g + r);
        #pragma unroll
        for (int nt = 0; nt < 5; ++nt) ctxa[rb][nt][r] *= fr;
      }
    LGKM0();   // P writes complete before same-wave P reads

    // ---- PV: ctx[q][d] += P[q][kk] * V[kk][d] ----
    {
      const _Float16* vcur = (kt & 1) ? Vb1 : Vb0;
      __builtin_amdgcn_s_setprio(1);
      #pragma unroll
      for (int kb4 = 0; kb4 < 2; ++kb4) {
        f16x8 pf0 = *(const f16x8*)&Pb[(w * 32 + ln) * 88 + kb4 * 32 + g * 8];
        f16x8 pf1 = *(const f16x8*)&Pb[(w * 32 + 16 + ln) * 88 + kb4 * 32 + g * 8];
        #pragma unroll
        for (int nt = 0; nt < 5; ++nt) {
          f16x8 vf = *(const f16x8*)&vcur[(nt * 16 + ln) * 72 + kb4 * 32 + g * 8];
          ctxa[0][nt] = __builtin_amdgcn_mfma_f32_16x16x32_f16(pf0, vf, ctxa[0][nt], 0, 0, 0);
          ctxa[1][nt] = __builtin_amdgcn_mfma_f32_16x16x32_f16(pf1, vf, ctxa[1][nt], 0, 0, 0);
        }
      }
      __builtin_amdgcn_s_setprio(0);
    }

    // ---- stage next tile, prefetch next-next ----
    stage(kt + 1);          // Kb safe (post BARRIER_A); V goes to other buffer
    LGKM0();
    BARRIER();              // B: staging visible for next iter
    issue(kt + 2 < 16 ? kt + 2 : 15);
  }

  // ---- epilogue ----
  #pragma unroll
  for (int rb = 0; rb < 2; ++rb)
    #pragma unroll
    for (int r = 0; r < 4; ++r) {
      float lr = __shfl(l_run, rb * 16 + 4 * g + r);
      float inv = 1.f / lr;
      int s = s0 + w * 32 + rb * 16 + 4 * g + r;
      int base = (s * 8 + bb) * 1280 + h16 * 80;
      #pragma unroll
      for (int nt = 0; nt < 5; ++nt)
        ctxg[base + nt * 16 + ln] = (_Float16)(ctxa[rb][nt][r] * inv);
    }
}

extern "C" void kernel_launch(void* const* d_in, const int* in_sizes, int n_in,
                              void* d_out, int out_size, void* d_ws, size_t ws_size,
                              hipStream_t stream) {
  const float* x     = (const float*)d_in[0];
  const float* w_in  = (const float*)d_in[1];
  const float* b_in  = (const float*)d_in[2];
  const float* w_out = (const float*)d_in[3];
  const float* b_out = (const float*)d_in[4];
  float* out = (float*)d_out;

  char* ws = (char*)d_ws;
  size_t off = 0;
  auto carve = [&](size_t bytes) -> void* {
    void* p = ws + off;
    off += (bytes + 255) & ~(size_t)255;
    return p;
  };
  _Float16* xb     = (_Float16*)carve(8192ull * 1280 * 2);
  _Float16* w_inT  = (_Float16*)carve(3840ull * 1280 * 2);
  _Float16* w_outT = (_Float16*)carve(1280ull * 1280 * 2);
  _Float16* qb     = (_Float16*)carve(128ull * 1024 * 80 * 2);
  _Float16* kbuf   = (_Float16*)carve(128ull * 1024 * 80 * 2);
  _Float16* vb     = (_Float16*)carve(128ull * 1024 * 80 * 2);
  _Float16* vT     = (_Float16*)carve(128ull * 1024 * 80 * 2);
  _Float16* ctxg   = (_Float16*)carve(8192ull * 1280 * 2);
  if (off > ws_size) return;

  hipFuncSetAttribute(reinterpret_cast<const void*>(&k_gemm8<8192, 3840, 1280>),
                      hipFuncAttributeMaxDynamicSharedMemorySize, 131072);
  hipFuncSetAttribute(reinterpret_cast<const void*>(&k_attn),
                      hipFuncAttributeMaxDynamicSharedMemorySize, 79360);

  k_cvt<<<2048, 256, 0, stream>>>(x, xb, 8192 * 1280 / 4);
  k_transpose<<<dim3(120, 40), 256, 0, stream>>>(w_in, w_inT, 1280, 3840);
  k_transpose<<<dim3(40, 40), 256, 0, stream>>>(w_out, w_outT, 1280, 1280);

  k_gemm8<8192, 3840, 1280><<<480, 512, 131072, stream>>>(xb, w_inT, b_in, qb, kbuf, vb);
  k_vtrans<<<2048, 256, 0, stream>>>(vb, vT);
  k_attn<<<512, 512, 79360, stream>>>(qb, kbuf, vT, ctxg);
  k_gemm<8192, 1280, 1280><<<dim3(64, 10), 256, 0, stream>>>(ctxg, w_outT, b_out, out);
}

// Round 6
// 255.690 us; speedup vs baseline: 1.2565x; 1.0437x over previous
//
#include <hip/hip_runtime.h>

#define DEVI __device__ __forceinline__

typedef _Float16 f16x8 __attribute__((ext_vector_type(8)));
typedef _Float16 f16x4v __attribute__((ext_vector_type(4)));
typedef _Float16 f16x2 __attribute__((ext_vector_type(2)));
typedef __fp16 fp16x2 __attribute__((ext_vector_type(2)));
typedef float f32x4 __attribute__((ext_vector_type(4)));
typedef float f32x16 __attribute__((ext_vector_type(16)));
typedef unsigned u32x4 __attribute__((ext_vector_type(4)));

DEVI void gl16(const void* g, void* l) {
  __builtin_amdgcn_global_load_lds((const __attribute__((address_space(1))) void*)g,
                                   (__attribute__((address_space(3))) void*)l, 16, 0, 0);
}

#define VMCNT(N) asm volatile("s_waitcnt vmcnt(" #N ")" ::: "memory")
#define LGKM0() asm volatile("s_waitcnt lgkmcnt(0)" ::: "memory")
#define BARRIER() asm volatile("s_barrier" ::: "memory")

DEVI unsigned pk2(float a, float b) {
  fp16x2 t = __builtin_amdgcn_cvt_pkrtz(a, b);
  return __builtin_bit_cast(unsigned, t);
}
DEVI void pl32swap(unsigned &a, unsigned &b) {
  asm volatile("v_permlane32_swap_b32 %0, %1" : "+v"(a), "+v"(b));
}

// ---------------- f32 -> f16 convert ----------------
__global__ __launch_bounds__(256) void k_cvt(const float* __restrict__ in, _Float16* __restrict__ out, int n4) {
  int i = blockIdx.x * 256 + threadIdx.x;
  int stride = gridDim.x * 256;
  for (; i < n4; i += stride) {
    float4 v = ((const float4*)in)[i];
    f16x4v h = { (_Float16)v.x, (_Float16)v.y, (_Float16)v.z, (_Float16)v.w };
    ((f16x4v*)out)[i] = h;
  }
}

// ---------------- transpose + convert: in[R][C] f32 -> out[C][R] f16 ----------------
__global__ __launch_bounds__(256) void k_transpose(const float* __restrict__ in, _Float16* __restrict__ out,
                                                   int R, int C) {
  __shared__ float t[32][33];
  int cb = blockIdx.x * 32, rb = blockIdx.y * 32;
  int tx = threadIdx.x & 31, ty = threadIdx.x >> 5;
  #pragma unroll
  for (int i = ty; i < 32; i += 8) t[i][tx] = in[(size_t)(rb + i) * C + cb + tx];
  __syncthreads();
  #pragma unroll
  for (int i = ty; i < 32; i += 8) out[(size_t)(cb + i) * R + rb + tx] = (_Float16)t[tx][i];
}

// ================= 256x256 8-phase GEMM (qkv producer) =================

#define MM(NLO, AF, BF) do {                                                                       \
    __builtin_amdgcn_s_setprio(1);                                                                 \
    _Pragma("unroll")                                                                              \
    for (int m_ = 0; m_ < 8; m_++) {                                                               \
      acc[m_][NLO]     = __builtin_amdgcn_mfma_f32_16x16x32_f16(AF[m_], BF[NLO],     acc[m_][NLO],     0, 0, 0); \
      acc[m_][NLO + 1] = __builtin_amdgcn_mfma_f32_16x16x32_f16(AF[m_], BF[NLO + 1], acc[m_][NLO + 1], 0, 0, 0); \
    }                                                                                              \
    __builtin_amdgcn_s_setprio(0);                                                                 \
  } while (0)

#define LDA(KT, KK, DST) do {                                                                      \
    const _Float16* bas_ = &smem[(size_t)((((KT) & 1) * 2) + wr) * 8192];                          \
    _Pragma("unroll")                                                                              \
    for (int m_ = 0; m_ < 8; m_++)                                                                 \
      DST[m_] = *(const f16x8*)&bas_[(m_ * 16 + ln) * 64 + (((((KK) * 4) + g) ^ chB) << 3)];       \
  } while (0)

#define LDB(KT, KK, DST) do {                                                                      \
    const _Float16* bas_ = &smem[32768 + (size_t)((((KT) & 1) * 2) + (wc >> 1)) * 8192];           \
    _Pragma("unroll")                                                                              \
    for (int n_ = 0; n_ < 4; n_++)                                                                 \
      DST[n_] = *(const f16x8*)&bas_[((wc & 1) * 64 + n_ * 16 + ln) * 64 + (((((KK) * 4) + g) ^ chB) << 3)]; \
  } while (0)

template<int M, int N, int K>
__global__ __launch_bounds__(512, 2) void k_gemm8(const _Float16* __restrict__ A, const _Float16* __restrict__ BT,
                                                  const float* __restrict__ bias,
                                                  _Float16* __restrict__ qo, _Float16* __restrict__ ko,
                                                  _Float16* __restrict__ vo) {
  extern __shared__ _Float16 smem[];
  constexpr int NT = K / 64;
  constexpr int NI = NT / 2;
  const int tid = threadIdx.x;
  const int w = tid >> 6, lane = tid & 63, ln = lane & 15, g = lane >> 4;
  const int wr = w >> 2, wc = w & 3;
  const int l8 = lane >> 3, l7 = lane & 7;
  const int stChunk = (l7 ^ l8) << 3;
  const int chB = ln & 7;

  constexpr int MT = M / 256;
  const int xcd = blockIdx.x & 7;
  const int i = blockIdx.x >> 3;
  const int bm0 = (xcd * (MT / 8) + (i & 3)) * 256;
  const int bn0 = (i >> 2) * 256;

  auto stgA = [&](int kt, int hh) {
    _Float16* ldsb = &smem[(size_t)((kt & 1) * 2 + hh) * 8192 + w * 1024];
    const _Float16* g0 = &A[(size_t)(bm0 + hh * 128 + w * 16 + l8) * K + kt * 64 + stChunk];
    gl16(g0, ldsb);
    gl16(g0 + (size_t)8 * K, ldsb + 512);
  };
  auto stgB = [&](int kt, int hh) {
    _Float16* ldsb = &smem[32768 + (size_t)((kt & 1) * 2 + hh) * 8192 + w * 1024];
    const _Float16* g0 = &BT[(size_t)(bn0 + hh * 128 + w * 16 + l8) * K + kt * 64 + stChunk];
    gl16(g0, ldsb);
    gl16(g0 + (size_t)8 * K, ldsb + 512);
  };

  f32x4 acc[8][4] = {};
  f16x8 a0[8], a1[8], b0[4], b1[4];

  stgB(0, 0); stgB(0, 1); stgA(0, 0); stgA(0, 1);
  stgB(1, 0); stgB(1, 1); stgA(1, 0);
  VMCNT(6);
  BARRIER();
  LDA(0, 0, a0); LDB(0, 0, b0);

  for (int it = 0; it < NI; ++it) {
    const int T0 = 2 * it, T1 = 2 * it + 1;
    const int S0 = (T0 + 2 < NT) ? T0 + 2 : 0;
    const int S1 = (T1 + 2 < NT) ? T1 + 2 : 1;
    LDB(T0, 1, b1);
    stgA(T1, 1);
    BARRIER();
    MM(0, a0, b0);
    LGKM0(); BARRIER();
    LDA(T0, 1, a1);
    stgB(S0, 0);
    BARRIER();
    MM(2, a0, b0);
    LGKM0(); BARRIER();
    stgB(S0, 1);
    BARRIER();
    MM(0, a1, b1);
    VMCNT(4);
    LGKM0(); BARRIER();
    LDA(T1, 0, a0); LDB(T1, 0, b0);
    stgA(S0, 0);
    BARRIER();
    MM(2, a1, b1);
    LGKM0(); BARRIER();
    LDB(T1, 1, b1);
    stgA(S0, 1);
    BARRIER();
    MM(0, a0, b0);
    LGKM0(); BARRIER();
    LDA(T1, 1, a1);
    stgB(S1, 0);
    BARRIER();
    MM(2, a0, b0);
    LGKM0(); BARRIER();
    stgB(S1, 1);
    BARRIER();
    MM(0, a1, b1);
    VMCNT(4);
    LGKM0(); BARRIER();
    LDA(S0, 0, a0); LDB(S0, 0, b0);
    stgA(S1, 0);
    BARRIER();
    MM(2, a1, b1);
    LGKM0(); BARRIER();
  }

  // epilogue: acc -> LDS f16 [256][256] -> coalesced 16B q/k/v stores
  VMCNT(0);
  BARRIER();
  _Float16* sH = smem;
  #pragma unroll
  for (int n = 0; n < 4; n++) {
    int col = wc * 64 + n * 16 + ln;
    int gcol = bn0 + col;
    float bv = bias[gcol];
    int hq = gcol / 240;
    int tt = gcol - hq * 240;
    // q gets 1/sqrt(80) * log2(e) so attention works in exp2 domain
    float scl = (tt < 80) ? (0.11180339887498948f * 1.4426950408889634f) : 1.0f;
    #pragma unroll
    for (int m = 0; m < 8; m++) {
      #pragma unroll
      for (int r = 0; r < 4; r++) {
        int row = wr * 128 + m * 16 + 4 * g + r;
        sH[row * 256 + col] = (_Float16)((acc[m][n][r] + bv) * scl);
      }
    }
  }
  LGKM0();
  BARRIER();
  #pragma unroll
  for (int i2 = 0; i2 < 16; i2++) {
    int id = tid + 512 * i2;
    int row = id >> 5, c8 = id & 31;
    f16x8 v = *(const f16x8*)&sH[row * 256 + c8 * 8];
    int gcol = bn0 + c8 * 8;
    int grow = bm0 + row;
    int hq = gcol / 240;
    int tt = gcol - hq * 240;
    int reg = tt / 80;
    int cc = tt - reg * 80;
    int s = grow >> 3;
    int head = (grow & 7) * 16 + hq;
    _Float16* dst = (reg == 0) ? qo : (reg == 1) ? ko : vo;
    *(f16x8*)&dst[(size_t)(head * 1024 + s) * 80 + cc] = v;
  }
}

// ---------------- 128x128 GEMM (out_proj) ----------------
template<int M, int N, int K>
__global__ __launch_bounds__(256) void k_gemm(const _Float16* __restrict__ A, const _Float16* __restrict__ BT,
                                              const float* __restrict__ bias, float* __restrict__ outF) {
  __shared__ _Float16 Al[128 * 32];
  __shared__ _Float16 Bl[128 * 32];
  const int tid = threadIdx.x;
  const int w = tid >> 6, lane = tid & 63, ln = lane & 15, g = lane >> 4;
  const int bm0 = blockIdx.x * 128, bn0 = blockIdx.y * 128;
  const int wm = (w >> 1) * 64, wn = (w & 1) * 64;
  const int r0 = tid >> 2, c0 = (tid & 3) * 8;
  f32x4 acc[4][4] = {};
  for (int kt = 0; kt < K; kt += 32) {
    __syncthreads();
    gl16(&A[(size_t)(bm0 + r0) * K + kt + c0],      &Al[(w * 64) * 8]);
    gl16(&A[(size_t)(bm0 + r0 + 64) * K + kt + c0], &Al[(256 + w * 64) * 8]);
    gl16(&BT[(size_t)(bn0 + r0) * K + kt + c0],      &Bl[(w * 64) * 8]);
    gl16(&BT[(size_t)(bn0 + r0 + 64) * K + kt + c0], &Bl[(256 + w * 64) * 8]);
    __syncthreads();
    f16x8 af[4], bf[4];
    #pragma unroll
    for (int i = 0; i < 4; i++) af[i] = *(const f16x8*)&Al[(wm + i * 16 + ln) * 32 + g * 8];
    #pragma unroll
    for (int i = 0; i < 4; i++) bf[i] = *(const f16x8*)&Bl[(wn + i * 16 + ln) * 32 + g * 8];
    #pragma unroll
    for (int i = 0; i < 4; i++)
      #pragma unroll
      for (int j = 0; j < 4; j++)
        acc[i][j] = __builtin_amdgcn_mfma_f32_16x16x32_f16(af[i], bf[j], acc[i][j], 0, 0, 0);
  }
  #pragma unroll
  for (int j = 0; j < 4; j++) {
    int col = bn0 + wn + j * 16 + ln;
    float bv = bias[col];
    #pragma unroll
    for (int i = 0; i < 4; i++) {
      int mb = bm0 + wm + i * 16 + 4 * g;
      #pragma unroll
      for (int r = 0; r < 4; r++)
        outF[(size_t)(mb + r) * N + col] = acc[i][j][r] + bv;
    }
  }
}

// ---------------- per-head V transpose ----------------
__global__ __launch_bounds__(256) void k_vtrans(const _Float16* __restrict__ vb, _Float16* __restrict__ vT) {
  __shared__ _Float16 t[64][81];
  int head = blockIdx.x >> 4;
  int sb = (blockIdx.x & 15) * 64;
  for (int idx = threadIdx.x; idx < 64 * 80; idx += 256) {
    int s = idx / 80, d = idx - s * 80;
    t[s][d] = vb[(head * 1024 + sb + s) * 80 + d];
  }
  __syncthreads();
  for (int idx = threadIdx.x; idx < 80 * 64; idx += 256) {
    int d = idx >> 6, s = idx & 63;
    vT[(head * 80 + d) * 1024 + sb + s] = t[s][d];
  }
}

// ---------------- flash attention: QBLK=256, 8 waves x 32 q-rows, in-register softmax ----------------
// qb/kb: [head][1024][80] f16 (q pre-scaled by log2e/sqrt(80)), vT: [head][80][1024]
// QK: S^T = mfma32x32x16(K, Q) -> lane holds col q=l32.  P stays in registers:
// cvt_pkrtz + v_permlane32_swap redistribute into PV B-operand layout.
// PV (swapped): ctx^T = mfma32x32x16(V^T, P^T) -> q stays lane-local (no shfl for rescale/1/l).
// LDS: K 2x[64][128] + V^T 2x[96][64], XOR-swizzled (chunk ^= row&7). One barrier/iter.
__global__ __launch_bounds__(512, 2) void k_attn(const _Float16* __restrict__ qb, const _Float16* __restrict__ kb,
                                                 const _Float16* __restrict__ vT, _Float16* __restrict__ ctxg) {
  extern __shared__ _Float16 smem[];
  _Float16* Kb0 = smem;                    // [64][128]
  _Float16* Kb1 = smem + 8192;
  _Float16* Vb0 = smem + 16384;            // [96][64]; rows 80..95 never written/stored
  _Float16* Vb1 = smem + 16384 + 6144;

  const int tid = threadIdx.x;
  const int w = tid >> 6, lane = tid & 63;
  const int l32 = lane & 31, h = lane >> 5;
  const int lx = l32 & 7;                  // read-side XOR key
  const int xcd = blockIdx.x & 7;
  const int j = blockIdx.x >> 3;
  const int head = xcd + 8 * (j & 15);
  const int s0 = (j >> 4) * 256;
  const int bb = head >> 4, h16 = head & 15;

  // staging: K 640 chunks (64 rows x 10), V 640 chunks (80 rows x 8); 2 K + 2 V per thread
  const int c1 = (tid < 128) ? tid + 512 : tid;
  const int kr0 = tid / 10, kh0 = tid - kr0 * 10;
  const int kr1 = c1 / 10,  kh1 = c1 - kr1 * 10;
  const int vr0 = tid >> 3, vh0 = tid & 7;
  const int vr1 = c1 >> 3,  vh1 = c1 & 7;
  const int kO0 = kr0 * 128 + ((kh0 ^ (kr0 & 7)) << 3);
  const int kO1 = kr1 * 128 + ((kh1 ^ (kr1 & 7)) << 3);
  const int vO0 = vr0 * 64 + ((vh0 ^ (vr0 & 7)) << 3);
  const int vO1 = vr1 * 64 + ((vh1 ^ (vr1 & 7)) << 3);
  const _Float16* kG0 = kb + (size_t)head * 81920 + kr0 * 80 + kh0 * 8;
  const _Float16* kG1 = kb + (size_t)head * 81920 + kr1 * 80 + kh1 * 8;
  const _Float16* vG0 = vT + (size_t)head * 81920 + vr0 * 1024 + vh0 * 8;
  const _Float16* vG1 = vT + (size_t)head * 81920 + vr1 * 1024 + vh1 * 8;

  uint4 krA, krB, vrA, vrB;
  auto issue = [&](int kt) {
    krA = *(const uint4*)(kG0 + kt * 5120);
    krB = *(const uint4*)(kG1 + kt * 5120);
    vrA = *(const uint4*)(vG0 + kt * 64);
    vrB = *(const uint4*)(vG1 + kt * 64);
  };
  auto stage = [&](int b) {
    _Float16* kd = b ? Kb1 : Kb0;
    _Float16* vd = b ? Vb1 : Vb0;
    *(uint4*)(kd + kO0) = krA;
    *(uint4*)(kd + kO1) = krB;
    *(uint4*)(vd + vO0) = vrA;
    *(uint4*)(vd + vO1) = vrB;
  };

  // Q fragment (B-operand): col q = l32, k = h*8+j per 16-slice
  const int qrow = s0 + w * 32 + l32;
  f16x8 qf[5];
  #pragma unroll
  for (int s = 0; s < 5; s++)
    qf[s] = *(const f16x8*)&qb[(size_t)(head * 1024 + qrow) * 80 + s * 16 + h * 8];

  f32x16 ct[3] = {};
  float m_run = -INFINITY, l_run = 0.f;

  issue(0);
  stage(0);
  LGKM0();
  BARRIER();
  issue(1);

  for (int kt = 0; kt < 16; ++kt) {
    const _Float16* kc = (kt & 1) ? Kb1 : Kb0;
    const _Float16* vc = (kt & 1) ? Vb1 : Vb0;

    // ---- QK^T: lane holds S[kk][q=l32]; kk = t*32 + (reg&3)+8*(reg>>2)+4h ----
    f32x16 sc0 = {}, sc1 = {};
    __builtin_amdgcn_s_setprio(1);
    #pragma unroll
    for (int s = 0; s < 5; ++s) {
      f16x8 kf0 = *(const f16x8*)&kc[l32 * 128 + (((2 * s + h) ^ lx) << 3)];
      f16x8 kf1 = *(const f16x8*)&kc[(32 + l32) * 128 + (((2 * s + h) ^ lx) << 3)];
      sc0 = __builtin_amdgcn_mfma_f32_32x32x16_f16(kf0, qf[s], sc0, 0, 0, 0);
      sc1 = __builtin_amdgcn_mfma_f32_32x32x16_f16(kf1, qf[s], sc1, 0, 0, 0);
    }
    __builtin_amdgcn_s_setprio(0);

    // ---- online softmax (exp2 domain), q lane-local ----
    float mx[8];
    #pragma unroll
    for (int i = 0; i < 8; ++i)
      mx[i] = fmaxf(fmaxf(sc0[i], sc0[i + 8]), fmaxf(sc1[i], sc1[i + 8]));
    #pragma unroll
    for (int i = 0; i < 4; ++i) mx[i] = fmaxf(mx[i], mx[i + 4]);
    float tm = fmaxf(fmaxf(mx[0], mx[2]), fmaxf(mx[1], mx[3]));
    tm = fmaxf(tm, __shfl_xor(tm, 32));
    float mnew = fmaxf(m_run, tm);
    float fac = exp2f(m_run - mnew);
    float p0[16], p1[16];
    #pragma unroll
    for (int i = 0; i < 16; ++i) p0[i] = exp2f(sc0[i] - mnew);
    #pragma unroll
    for (int i = 0; i < 16; ++i) p1[i] = exp2f(sc1[i] - mnew);
    float ps = 0.f;
    #pragma unroll
    for (int i = 0; i < 16; ++i) ps += p0[i] + p1[i];

    // ---- pack P to f16 + permlane32_swap into PV B-fragments: fr[ss][j] = P[32*(ss>>1)+16*(ss&1)+8h+j][q] ----
    unsigned fr[4][4];
    #define PACK4(T, PP) do {                                                \
        _Pragma("unroll")                                                    \
        for (int s16 = 0; s16 < 2; ++s16) {                                  \
          unsigned u0 = pk2(PP[8 * s16 + 0], PP[8 * s16 + 1]);               \
          unsigned u1 = pk2(PP[8 * s16 + 2], PP[8 * s16 + 3]);               \
          unsigned u2 = pk2(PP[8 * s16 + 4], PP[8 * s16 + 5]);               \
          unsigned u3 = pk2(PP[8 * s16 + 6], PP[8 * s16 + 7]);               \
          pl32swap(u0, u2); pl32swap(u1, u3);                                \
          fr[2 * (T) + s16][0] = u0; fr[2 * (T) + s16][1] = u1;              \
          fr[2 * (T) + s16][2] = u2; fr[2 * (T) + s16][3] = u3;              \
        }                                                                    \
      } while (0)
    PACK4(0, p0);
    PACK4(1, p1);

    l_run = l_run * fac + (ps + __shfl_xor(ps, 32));
    m_run = mnew;

    // ---- rescale ctx^T (q = l32 lane-local: no shuffles) ----
    #pragma unroll
    for (int dt = 0; dt < 3; ++dt)
      #pragma unroll
      for (int i = 0; i < 16; ++i) ct[dt][i] *= fac;

    // ---- PV: ctx^T[d][q] += V^T[d][kk] * P^T[kk][q] ----
    __builtin_amdgcn_s_setprio(1);
    #pragma unroll
    for (int ss = 0; ss < 4; ++ss) {
      u32x4 fu = { fr[ss][0], fr[ss][1], fr[ss][2], fr[ss][3] };
      f16x8 pf = __builtin_bit_cast(f16x8, fu);
      #pragma unroll
      for (int dt = 0; dt < 3; ++dt) {
        f16x8 vf = *(const f16x8*)&vc[(dt * 32 + l32) * 64 + (((2 * ss + h) ^ lx) << 3)];
        ct[dt] = __builtin_amdgcn_mfma_f32_32x32x16_f16(vf, pf, ct[dt], 0, 0, 0);
      }
    }
    __builtin_amdgcn_s_setprio(0);

    // ---- stage next tile (other buffers), single barrier, prefetch next-next ----
    if (kt < 15) {
      stage((kt + 1) & 1);
      LGKM0();
      BARRIER();
      if (kt < 14) issue(kt + 2);
    }
  }

  // ---- epilogue: lane owns column q; d = dt*32 + rq*8 + 4h + 0..3 (skip d>=80) ----
  float inv = 1.f / l_run;
  int sq = s0 + w * 32 + l32;
  _Float16* outp = ctxg + (size_t)(sq * 8 + bb) * 1280 + h16 * 80 + 4 * h;
  #pragma unroll
  for (int dt = 0; dt < 3; ++dt)
    #pragma unroll
    for (int rq = 0; rq < 4; ++rq) {
      if (dt == 2 && rq >= 2) continue;
      f16x4v o = { (_Float16)(ct[dt][rq * 4 + 0] * inv), (_Float16)(ct[dt][rq * 4 + 1] * inv),
                   (_Float16)(ct[dt][rq * 4 + 2] * inv), (_Float16)(ct[dt][rq * 4 + 3] * inv) };
      *(f16x4v*)&outp[dt * 32 + rq * 8] = o;
    }
}

extern "C" void kernel_launch(void* const* d_in, const int* in_sizes, int n_in,
                              void* d_out, int out_size, void* d_ws, size_t ws_size,
                              hipStream_t stream) {
  const float* x     = (const float*)d_in[0];
  const float* w_in  = (const float*)d_in[1];
  const float* b_in  = (const float*)d_in[2];
  const float* w_out = (const float*)d_in[3];
  const float* b_out = (const float*)d_in[4];
  float* out = (float*)d_out;

  char* ws = (char*)d_ws;
  size_t off = 0;
  auto carve = [&](size_t bytes) -> void* {
    void* p = ws + off;
    off += (bytes + 255) & ~(size_t)255;
    return p;
  };
  _Float16* xb     = (_Float16*)carve(8192ull * 1280 * 2);
  _Float16* w_inT  = (_Float16*)carve(3840ull * 1280 * 2);
  _Float16* w_outT = (_Float16*)carve(1280ull * 1280 * 2);
  _Float16* qb     = (_Float16*)carve(128ull * 1024 * 80 * 2);
  _Float16* kbuf   = (_Float16*)carve(128ull * 1024 * 80 * 2);
  _Float16* vb     = (_Float16*)carve(128ull * 1024 * 80 * 2);
  _Float16* vT     = (_Float16*)carve(128ull * 1024 * 80 * 2);
  _Float16* ctxg   = (_Float16*)carve(8192ull * 1280 * 2);
  if (off > ws_size) return;

  hipFuncSetAttribute(reinterpret_cast<const void*>(&k_gemm8<8192, 3840, 1280>),
                      hipFuncAttributeMaxDynamicSharedMemorySize, 131072);
  hipFuncSetAttribute(reinterpret_cast<const void*>(&k_attn),
                      hipFuncAttributeMaxDynamicSharedMemorySize, 57344);

  k_cvt<<<2048, 256, 0, stream>>>(x, xb, 8192 * 1280 / 4);
  k_transpose<<<dim3(120, 40), 256, 0, stream>>>(w_in, w_inT, 1280, 3840);
  k_transpose<<<dim3(40, 40), 256, 0, stream>>>(w_out, w_outT, 1280, 1280);

  k_gemm8<8192, 3840, 1280><<<480, 512, 131072, stream>>>(xb, w_inT, b_in, qb, kbuf, vb);
  k_vtrans<<<2048, 256, 0, stream>>>(vb, vT);
  k_attn<<<512, 512, 57344, stream>>>(qb, kbuf, vT, ctxg);
  k_gemm<8192, 1280, 1280><<<dim3(64, 10), 256, 0, stream>>>(ctxg, w_outT, b_out, out);
}